// Round 2
// baseline (780.534 us; speedup 1.0000x reference)
//
#include <hip/hip_runtime.h>
#include <hip/hip_bf16.h>

// StackedLoRALinear on MI355X (gfx950). Inputs/outputs fp32 (per reference);
// compute in bf16 MFMA (tolerance is bf16-class: 2% rel).
//
// out[M,N] = x[M,K] @ W[N,K]^T + b[N] + z[M,128] @ B'[N,128]^T
//   z  = x @ lora_A^T        (lora_A flat = [128, K] row-major)
//   B'[n, d*32+r] = lora_B[d, n, r]
//
// Pipeline: fp32->bf16 convert (x, W, lora_A) + transpose-convert lora_B,
// then m97-style 128x128 bf16 MFMA GEMMs (16x16x32, global_load_lds w=16),
// LoRA folded into the main GEMM as 4 extra K-iterations. fp32 epilogue.

typedef unsigned short ushort_t;
typedef short bf16x8 __attribute__((ext_vector_type(8)));   // 8 bf16 = 4 VGPRs
typedef float floatx4 __attribute__((ext_vector_type(4)));
typedef unsigned short ushortx4 __attribute__((ext_vector_type(4)));

__device__ __forceinline__ ushort_t f2bf(float f) {
    __hip_bfloat16 h = __float2bfloat16(f);
    return *(ushort_t*)&h;
}

__device__ __forceinline__ void async_load16(const void* g, void* l) {
    __builtin_amdgcn_global_load_lds(
        (const __attribute__((address_space(1))) void*)g,
        (__attribute__((address_space(3))) void*)l,
        16, 0, 0);
}

// fp32 -> bf16, 4 elements/thread (16B load, 8B store). n4 = n/4.
__global__ __launch_bounds__(256)
void cvt_kernel(const float* __restrict__ in, ushort_t* __restrict__ out, int n4) {
    int i = blockIdx.x * 256 + threadIdx.x;
    if (i < n4) {
        const float4 v = ((const float4*)in)[i];
        ushortx4 o = { f2bf(v.x), f2bf(v.y), f2bf(v.z), f2bf(v.w) };
        ((ushortx4*)out)[i] = o;
    }
}

// B'[n*128 + d*32 + r] = bf16(lora_B[d*N*32 + n*32 + r]);  N=3072
__global__ __launch_bounds__(256)
void transpose_loraB_kernel(const float* __restrict__ lb,
                            ushort_t* __restrict__ out) {
    int idx = blockIdx.x * 256 + threadIdx.x;   // 0 .. 393215
    int n = idx >> 7;
    int j = idx & 127;          // d*32 + r
    int d = j >> 5, r = j & 31;
    out[idx] = f2bf(lb[(size_t)d * (3072 * 32) + (size_t)n * 32 + r]);
}

// "B-transposed" bf16 GEMM: C[m,n] = sum_k A[m,k]*B[n,k] (+ phase-2 A2/B2, + bias).
// Block = 256 threads = 4 waves; tile 128x128; BK=32; wave -> 64x64 (4x4 MFMAs).
template <int KT1, int KT2, bool OUT_F32>
__global__ __launch_bounds__(256)
void gemm_bt_kernel(const ushort_t* __restrict__ A, int lda,
                    const ushort_t* __restrict__ B, int ldb,
                    const ushort_t* __restrict__ A2,   // [.,128] bf16 or null
                    const ushort_t* __restrict__ B2,   // [.,128] bf16 or null
                    const float* __restrict__ bias,    // [N] fp32 or null
                    void* __restrict__ Cv, int ldc)
{
    __shared__ ushort_t As[128 * 32];   // 8 KB
    __shared__ ushort_t Bs[128 * 32];   // 8 KB

    const int t    = threadIdx.x;
    const int lane = t & 63;
    const int wave = t >> 6;
    const int wr   = wave >> 1, wc = wave & 1;
    const int quad = lane >> 4, l16 = lane & 15;

    const int mBase = blockIdx.y * 128;
    const int nBase = blockIdx.x * 128;

    floatx4 acc[4][4] = {};

    // Staging: tile is 128 rows x 32 cols bf16 = 512 chunks of 16 B.
    // Chunk c -> row c>>2, col (c&3)*8; LDS byte offset = c*16, so each wave's
    // dests are wave-uniform-base + lane*16 (global_load_lds constraint OK).
    const int c0 = t,        r0 = c0 >> 2, col0 = (c0 & 3) << 3;
    const int c1 = t + 256,  r1 = c1 >> 2, col1 = (c1 & 3) << 3;

    for (int kt = 0; kt < KT1 + KT2; ++kt) {
        const ushort_t* ap; const ushort_t* bp; int la, lb_, ko;
        if (kt < KT1) { ap = A;  la = lda; bp = B;  lb_ = ldb; ko = kt * 32; }
        else          { ap = A2; la = 128; bp = B2; lb_ = 128; ko = (kt - KT1) * 32; }

        async_load16(ap + (size_t)(mBase + r0) * la + ko + col0, &As[c0 * 8]);
        async_load16(ap + (size_t)(mBase + r1) * la + ko + col1, &As[c1 * 8]);
        async_load16(bp + (size_t)(nBase + r0) * lb_ + ko + col0, &Bs[c0 * 8]);
        async_load16(bp + (size_t)(nBase + r1) * lb_ + ko + col1, &Bs[c1 * 8]);

        __syncthreads();   // drains vmcnt -> staged data visible

        bf16x8 af[4], bf[4];
#pragma unroll
        for (int mi = 0; mi < 4; ++mi)
            af[mi] = *(const bf16x8*)&As[(wr * 64 + mi * 16 + l16) * 32 + quad * 8];
#pragma unroll
        for (int ni = 0; ni < 4; ++ni)
            bf[ni] = *(const bf16x8*)&Bs[(wc * 64 + ni * 16 + l16) * 32 + quad * 8];

#pragma unroll
        for (int mi = 0; mi < 4; ++mi)
#pragma unroll
            for (int ni = 0; ni < 4; ++ni)
                acc[mi][ni] = __builtin_amdgcn_mfma_f32_16x16x32_bf16(
                    af[mi], bf[ni], acc[mi][ni], 0, 0, 0);

        __syncthreads();   // all waves done reading LDS before next overwrite
    }

    // Epilogue. C/D layout (verified m89/m91): col = lane&15, row = quad*4 + reg.
#pragma unroll
    for (int ni = 0; ni < 4; ++ni) {
        const int col = nBase + wc * 64 + ni * 16 + l16;
        const float bv = bias ? bias[col] : 0.0f;
#pragma unroll
        for (int mi = 0; mi < 4; ++mi) {
            const int row = mBase + wr * 64 + mi * 16 + quad * 4;
#pragma unroll
            for (int r = 0; r < 4; ++r) {
                const float v = acc[mi][ni][r] + bv;
                if (OUT_F32) {
                    ((float*)Cv)[(size_t)(row + r) * ldc + col] = v;
                } else {
                    ((ushort_t*)Cv)[(size_t)(row + r) * ldc + col] = f2bf(v);
                }
            }
        }
    }
}

extern "C" void kernel_launch(void* const* d_in, const int* in_sizes, int n_in,
                              void* d_out, int out_size, void* d_ws, size_t ws_size,
                              hipStream_t stream) {
    // Inputs (fp32): x[4,4096,3072], W[3072,3072], b[3072],
    //                lora_A[4,32,3072], lora_B[4,3072,32]
    const float* x  = (const float*)d_in[0];
    const float* W  = (const float*)d_in[1];
    const float* b  = (const float*)d_in[2];
    const float* lA = (const float*)d_in[3];
    const float* lB = (const float*)d_in[4];
    float* out = (float*)d_out;

    constexpr int M = 4 * 4096;        // 16384
    constexpr int N = 3072;
    constexpr int K = 3072;            // 96 iters of BK=32; LoRA adds 4 more
    constexpr size_t nX  = (size_t)M * K;       // 50331648
    constexpr size_t nW  = (size_t)N * K;       //  9437184
    constexpr size_t nLA = (size_t)128 * K;     //   393216
    constexpr size_t nLB = (size_t)128 * N;     //   393216

    // Workspace layout (bf16 elements): xb | Wb | lAb | Bp | z
    ushort_t* xb  = (ushort_t*)d_ws;
    ushort_t* Wb  = xb  + nX;
    ushort_t* lAb = Wb  + nW;
    ushort_t* Bp  = lAb + nLA;
    ushort_t* z   = Bp  + nLB;          // [M,128] bf16

    // 1) fp32 -> bf16 conversions
    cvt_kernel<<<nX  / 4 / 256, 256, 0, stream>>>(x,  xb,  (int)(nX  / 4));
    cvt_kernel<<<nW  / 4 / 256, 256, 0, stream>>>(W,  Wb,  (int)(nW  / 4));
    cvt_kernel<<<nLA / 4 / 256, 256, 0, stream>>>(lA, lAb, (int)(nLA / 4));

    // 2) B' transpose+convert
    transpose_loraB_kernel<<<nLB / 256, 256, 0, stream>>>(lB, Bp);

    // 3) z = x @ lora_A^T  (bf16 out, one column tile)
    gemm_bt_kernel<96, 0, false><<<dim3(1, M / 128), 256, 0, stream>>>(
        xb, K, lAb, K, nullptr, nullptr, nullptr, z, 128);

    // 4) out = x @ W^T + b + z @ B'^T  (fp32 out)
    gemm_bt_kernel<96, 4, true><<<dim3(N / 128, M / 128), 256, 0, stream>>>(
        xb, K, Wb, K, z, Bp, b, out, N);
}

// Round 3
// 723.429 us; speedup vs baseline: 1.0789x; 1.0789x over previous
//
#include <hip/hip_runtime.h>
#include <hip/hip_bf16.h>

// StackedLoRALinear on MI355X (gfx950). fp32 in/out, bf16 MFMA inside.
//
// Algebraic fold: out = x @ Weff^T + b, where
//   Weff = W + B' @ A_all,  B'[n,j=d*32+r] = lora_B[d,n,r],  A_all = lora_A flat [128,3072]
// Pipeline:
//   1. cvt x -> bf16                     (HBM-bound, ~60 us)
//   2. transpose-convert lora_B -> B'    (bf16 [3072,128])
//   3. transpose-convert lora_A -> A^T   (bf16 [3072,128])
//   4. Weff = B' @ (A^T)^T + W  via MFMA GEMM (KT=4, ADD_MAT epilogue, bf16 out)
//   5. out = xb @ Weff^T + b     via MFMA GEMM (KT=96, fp32 out)
// GEMM: m97 structure + LDS chunk swizzle to kill ds_read_b128 bank conflicts
// (slot p holds global chunk (p&3)^((row>>1)&3); write side stays linear as
// global_load_lds requires).

typedef unsigned short ushort_t;
typedef short bf16x8 __attribute__((ext_vector_type(8)));   // 8 bf16 = 4 VGPRs
typedef float floatx4 __attribute__((ext_vector_type(4)));
typedef unsigned short ushortx4 __attribute__((ext_vector_type(4)));

__device__ __forceinline__ ushort_t f2bf(float f) {
    __hip_bfloat16 h = __float2bfloat16(f);
    return *(ushort_t*)&h;
}

__device__ __forceinline__ void async_load16(const void* g, void* l) {
    __builtin_amdgcn_global_load_lds(
        (const __attribute__((address_space(1))) void*)g,
        (__attribute__((address_space(3))) void*)l,
        16, 0, 0);
}

// fp32 -> bf16, 4 elements/thread. n4 = n/4.
__global__ __launch_bounds__(256)
void cvt_kernel(const float* __restrict__ in, ushort_t* __restrict__ out, int n4) {
    int i = blockIdx.x * 256 + threadIdx.x;
    if (i < n4) {
        const float4 v = ((const float4*)in)[i];
        ushortx4 o = { f2bf(v.x), f2bf(v.y), f2bf(v.z), f2bf(v.w) };
        ((ushortx4*)out)[i] = o;
    }
}

// B'[n*128 + d*32 + r] = bf16(lora_B[d*N*32 + n*32 + r]);  N=3072
__global__ __launch_bounds__(256)
void transpose_loraB_kernel(const float* __restrict__ lb,
                            ushort_t* __restrict__ out) {
    int idx = blockIdx.x * 256 + threadIdx.x;   // 0 .. 393215
    int n = idx >> 7;
    int j = idx & 127;
    int d = j >> 5, r = j & 31;
    out[idx] = f2bf(lb[(size_t)d * (3072 * 32) + (size_t)n * 32 + r]);
}

// A^T[kk*128 + j] = bf16(lora_A[j*3072 + kk]);  (lora_A flat = [128,3072])
__global__ __launch_bounds__(256)
void transpose_loraA_kernel(const float* __restrict__ la,
                            ushort_t* __restrict__ out) {
    int idx = blockIdx.x * 256 + threadIdx.x;   // 0 .. 393215
    int kk = idx >> 7;
    int j  = idx & 127;
    out[idx] = f2bf(la[(size_t)j * 3072 + kk]);
}

// "B-transposed" bf16 MFMA GEMM: C[m,n] = sum_k A[m,k]*B[n,k] (+bias / +Cadd).
// Block = 256 threads = 4 waves; tile 128x128; BK=32; wave -> 64x64 (4x4 MFMAs).
template <int KT, bool OUT_F32, bool ADD_MAT>
__global__ __launch_bounds__(256)
void gemm_bt_kernel(const ushort_t* __restrict__ A, int lda,
                    const ushort_t* __restrict__ B, int ldb,
                    const float* __restrict__ Cadd,   // [M,ldc] fp32 if ADD_MAT
                    const float* __restrict__ bias,   // [N] fp32 or null
                    void* __restrict__ Cv, int ldc)
{
    __shared__ ushort_t As[128 * 32];   // 8 KB
    __shared__ ushort_t Bs[128 * 32];   // 8 KB

    const int t    = threadIdx.x;
    const int lane = t & 63;
    const int wave = t >> 6;
    const int wr   = wave >> 1, wc = wave & 1;
    const int quad = lane >> 4, l16 = lane & 15;

    const int mBase = blockIdx.y * 128;
    const int nBase = blockIdx.x * 128;

    floatx4 acc[4][4] = {};

    // Staging with bank swizzle. Tile = 128 rows x 4 chunks of 16 B.
    // LDS slot p (byte p*16) holds global chunk (row=p>>2, (p&3)^((row>>1)&3)).
    // Write side: dst = base + p*16 = wave-uniform + lane*16 (DMA constraint OK);
    // read side spreads the 16 lanes of each quad over all 8 bank-groups.
    const int p0 = t,       r0 = p0 >> 2, g0 = ((p0 & 3) ^ ((r0 >> 1) & 3)) << 3;
    const int p1 = t + 256, r1 = p1 >> 2, g1 = ((p1 & 3) ^ ((r1 >> 1) & 3)) << 3;

    // Fragment read column-swizzle: row = 16*X + l16 -> (row>>1)&3 == (l16>>1)&3
    const int qs = (quad ^ ((l16 >> 1) & 3)) << 3;

    for (int kt = 0; kt < KT; ++kt) {
        const int ko = kt * 32;

        async_load16(A + (size_t)(mBase + r0) * lda + ko + g0, &As[p0 * 8]);
        async_load16(A + (size_t)(mBase + r1) * lda + ko + g1, &As[p1 * 8]);
        async_load16(B + (size_t)(nBase + r0) * ldb + ko + g0, &Bs[p0 * 8]);
        async_load16(B + (size_t)(nBase + r1) * ldb + ko + g1, &Bs[p1 * 8]);

        __syncthreads();   // drains vmcnt -> staged data visible

        bf16x8 af[4], bf[4];
#pragma unroll
        for (int mi = 0; mi < 4; ++mi)
            af[mi] = *(const bf16x8*)&As[(wr * 64 + mi * 16 + l16) * 32 + qs];
#pragma unroll
        for (int ni = 0; ni < 4; ++ni)
            bf[ni] = *(const bf16x8*)&Bs[(wc * 64 + ni * 16 + l16) * 32 + qs];

#pragma unroll
        for (int mi = 0; mi < 4; ++mi)
#pragma unroll
            for (int ni = 0; ni < 4; ++ni)
                acc[mi][ni] = __builtin_amdgcn_mfma_f32_16x16x32_bf16(
                    af[mi], bf[ni], acc[mi][ni], 0, 0, 0);

        __syncthreads();   // all waves done reading LDS before next overwrite
    }

    // Epilogue. C/D layout (verified m89/m91): col = lane&15, row = quad*4 + reg.
#pragma unroll
    for (int ni = 0; ni < 4; ++ni) {
        const int col = nBase + wc * 64 + ni * 16 + l16;
        const float bv = bias ? bias[col] : 0.0f;
#pragma unroll
        for (int mi = 0; mi < 4; ++mi) {
            const int row = mBase + wr * 64 + mi * 16 + quad * 4;
#pragma unroll
            for (int r = 0; r < 4; ++r) {
                float v = acc[mi][ni][r] + bv;
                if (ADD_MAT) v += Cadd[(size_t)(row + r) * ldc + col];
                if (OUT_F32) {
                    ((float*)Cv)[(size_t)(row + r) * ldc + col] = v;
                } else {
                    ((ushort_t*)Cv)[(size_t)(row + r) * ldc + col] = f2bf(v);
                }
            }
        }
    }
}

extern "C" void kernel_launch(void* const* d_in, const int* in_sizes, int n_in,
                              void* d_out, int out_size, void* d_ws, size_t ws_size,
                              hipStream_t stream) {
    // Inputs (fp32): x[4,4096,3072], W[3072,3072], b[3072],
    //                lora_A[4,32,3072], lora_B[4,3072,32]
    const float* x  = (const float*)d_in[0];
    const float* W  = (const float*)d_in[1];
    const float* b  = (const float*)d_in[2];
    const float* lA = (const float*)d_in[3];
    const float* lB = (const float*)d_in[4];
    float* out = (float*)d_out;

    constexpr int M = 4 * 4096;        // 16384
    constexpr int N = 3072;
    constexpr int K = 3072;            // 96 iters of BK=32
    constexpr size_t nX  = (size_t)M * K;     // 50331648
    constexpr size_t nW  = (size_t)N * K;     //  9437184
    constexpr size_t nT  = (size_t)128 * K;   //   393216

    // Workspace (bf16 elems): xb | Weffb | Bp | At
    ushort_t* xb    = (ushort_t*)d_ws;
    ushort_t* Weffb = xb + nX;
    ushort_t* Bp    = Weffb + nW;
    ushort_t* At    = Bp + nT;

    // 1) x -> bf16
    cvt_kernel<<<nX / 4 / 256, 256, 0, stream>>>(x, xb, (int)(nX / 4));

    // 2,3) LoRA factor transposes (bf16 [3072,128], inner dim contiguous)
    transpose_loraB_kernel<<<nT / 256, 256, 0, stream>>>(lB, Bp);
    transpose_loraA_kernel<<<nT / 256, 256, 0, stream>>>(lA, At);

    // 4) Weff[n,kk] = sum_j B'[n,j]*A^T[kk,j] + W[n,kk], bf16 out. K=128 -> KT=4.
    gemm_bt_kernel<4, false, true><<<dim3(N / 128, N / 128), 256, 0, stream>>>(
        Bp, 128, At, 128, W, nullptr, Weffb, N);

    // 5) out = xb @ Weff^T + b, fp32 out. KT=96.
    gemm_bt_kernel<96, true, false><<<dim3(N / 128, M / 128), 256, 0, stream>>>(
        xb, K, Weffb, K, nullptr, b, out, N);
}